// Round 8
// baseline (20.492 us; speedup 1.0000x reference)
//
#include <hip/hip_runtime.h>
#include <math.h>

#define EPSF 1e-8f

constexpr int B = 512;
constexpr int F = 256;

using frag_ab = __attribute__((ext_vector_type(8))) short;   // 8 bf16
using f32x4   = __attribute__((ext_vector_type(4))) float;

__device__ __forceinline__ unsigned short f2bf(float f) {
    unsigned int u = __float_as_uint(f);
    unsigned int r = (u + 0x7fffu + ((u >> 16) & 1u)) >> 16;   // RNE
    return (unsigned short)r;
}

// ---- K1: fused norm + cos tile GEMM, 1 wave per 16x16 tile, 1024 blocks ---
// Iteration m loads row m of the panel fully coalesced (lane l = float4 #l),
// wave-allreduces the squared norm, scales+converts to bf16, and stages the
// row into LDS with the same XOR-swizzled chunk layout R7's MFMA path uses.
__global__ __launch_bounds__(64) void cos_fused(
    const float* __restrict__ feats, float* __restrict__ cosm)
{
    const int bid = blockIdx.x;
    const int it = bid >> 5, jt = bid & 31;      // 32x32 grid of 16x16 tiles
    const int l = threadIdx.x;

    __shared__ __align__(16) unsigned char Abf[16 * 512];   // 16 rows x 512 B
    __shared__ __align__(16) unsigned char Bbf[16 * 512];

    const float4* Ag = (const float4*)(feats + (size_t)(it * 16) * F);
    const float4* Bg = (const float4*)(feats + (size_t)(jt * 16) * F);

    const int chunk_off = (l >> 1) * 16 + (l & 1) * 8;  // lane's 8B slot (pre-swizzle)

    #pragma unroll
    for (int m = 0; m < 16; ++m) {
        const int swz = ((l >> 1) ^ (m & 7)) * 16 + (l & 1) * 8;

        float4 a = Ag[m * 64 + l];               // row m, fully coalesced
        float sa = a.x*a.x + a.y*a.y + a.z*a.z + a.w*a.w;
        #pragma unroll
        for (int o = 32; o > 0; o >>= 1) sa += __shfl_xor(sa, o);
        float inva = 1.f / fmaxf(sqrtf(sa + EPSF), EPSF);
        ushort4 ha = { f2bf(a.x*inva), f2bf(a.y*inva), f2bf(a.z*inva), f2bf(a.w*inva) };
        *(ushort4*)(Abf + m * 512 + swz) = ha;

        float4 b = Bg[m * 64 + l];
        float sb = b.x*b.x + b.y*b.y + b.z*b.z + b.w*b.w;
        #pragma unroll
        for (int o = 32; o > 0; o >>= 1) sb += __shfl_xor(sb, o);
        float invb = 1.f / fmaxf(sqrtf(sb + EPSF), EPSF);
        ushort4 hb = { f2bf(b.x*invb), f2bf(b.y*invb), f2bf(b.z*invb), f2bf(b.w*invb) };
        *(ushort4*)(Bbf + m * 512 + swz) = hb;
    }
    (void)chunk_off;
    // single wave: compiler orders ds_write -> ds_read via lgkmcnt

    const int row_f = l & 15;        // fragment row (A row / B row)
    const int kg    = l >> 4;        // k-group 0..3
    f32x4 acc = {0.f, 0.f, 0.f, 0.f};
    #pragma unroll
    for (int kc = 0; kc < 8; ++kc) {
        int cc = (kc * 4 + kg) ^ (row_f & 7);
        frag_ab a = *(const frag_ab*)(Abf + row_f * 512 + cc * 16);
        frag_ab b = *(const frag_ab*)(Bbf + row_f * 512 + cc * 16);
        acc = __builtin_amdgcn_mfma_f32_16x16x32_bf16(a, b, acc, 0, 0, 0);
    }
    // C layout (verified): col = lane&15, row = (lane>>4)*4 + j
    const int col = l & 15;
    #pragma unroll
    for (int j = 0; j < 4; ++j) {
        int row = kg * 4 + j;
        cosm[(size_t)(it * 16 + row) * B + jt * 16 + col] = acc[j];
    }
}

// ---- K2: per-row hinge sums (R7 verbatim) ---------------------------------
__global__ __launch_bounds__(256) void rows_kernel(
    const int* __restrict__ ids, const float* __restrict__ cosm,
    float* __restrict__ rowloss, int* __restrict__ rowvalid)
{
    const int i    = blockIdx.x;
    const int tid  = threadIdx.x;
    const int lane = tid & 63;
    const int wid  = tid >> 6;

    __shared__ int   dd[B];
    __shared__ float vals[B];
    __shared__ unsigned long long cmask[8];
    __shared__ int   coff[9];
    __shared__ float part_s[4], part_n[4];

    const int4 idi = ((const int4*)ids)[i];
    #pragma unroll
    for (int jj = 0; jj < 2; ++jj) {
        int j = tid + jj * 256;
        int4 idj = ((const int4*)ids)[j];
        dd[j] = abs(idi.x - idj.x) + abs(idi.y - idj.y)
              + abs(idi.z - idj.z) + abs(idi.w - idj.w);
    }
    __syncthreads();

    #pragma unroll
    for (int cc = 0; cc < 2; ++cc) {
        int chunk = wid * 2 + cc;
        int j = chunk * 64 + lane;
        unsigned long long m = __ballot((dd[j] == 0) && (j != i));
        if (lane == 0) cmask[chunk] = m;
    }
    __syncthreads();
    if (tid == 0) {
        int a = 0;
        #pragma unroll
        for (int c = 0; c < 8; ++c) { coff[c] = a; a += (int)__popcll(cmask[c]); }
        coff[8] = a;
    }
    __syncthreads();
    #pragma unroll
    for (int cc = 0; cc < 2; ++cc) {
        int chunk = wid * 2 + cc;
        int j = chunk * 64 + lane;
        unsigned long long m = cmask[chunk];
        if ((m >> lane) & 1ull) {
            int pos = coff[chunk] + (int)__popcll(m & ((1ull << lane) - 1ull));
            vals[pos] = cosm[(size_t)i * B + j];
        }
    }
    __syncthreads();

    const int ns = coff[8];
    const int d0 = dd[tid], d1 = dd[tid + 256];
    const bool m0 = d0 > 0, m1 = d1 > 0;
    const float b0 = 0.15f * (float)d0 + cosm[(size_t)i * B + tid];
    const float b1 = 0.15f * (float)d1 + cosm[(size_t)i * B + tid + 256];

    float s = 0.f;
    for (int t = 0; t < ns; ++t) {
        float a = vals[t];
        if (m0) s += fmaxf(0.f, b0 - a);
        if (m1) s += fmaxf(0.f, b1 - a);
    }
    float ndf = (m0 ? 1.f : 0.f) + (m1 ? 1.f : 0.f);

    #pragma unroll
    for (int o = 32; o > 0; o >>= 1) {
        s   += __shfl_down(s, o);
        ndf += __shfl_down(ndf, o);
    }
    if (lane == 0) { part_s[wid] = s; part_n[wid] = ndf; }
    __syncthreads();
    if (tid == 0) {
        float tot = part_s[0] + part_s[1] + part_s[2] + part_s[3];
        float nd  = part_n[0] + part_n[1] + part_n[2] + part_n[3];
        float cnt = (float)ns * nd;
        rowloss[i]  = (cnt > 0.f) ? tot / cnt : 0.f;
        rowvalid[i] = (cnt > 0.f) ? 1 : 0;
    }
}

// ---- K3: final mean over valid rows (verbatim) ----------------------------
__global__ __launch_bounds__(256) void finalize_kernel(
    const float* __restrict__ rowloss, const int* __restrict__ rowvalid,
    float* __restrict__ out)
{
    const int tid  = threadIdx.x;
    const int lane = tid & 63;
    const int wid  = tid >> 6;
    __shared__ float sb[4], vb[4];

    float s = rowloss[tid] + rowloss[tid + 256];
    float v = (float)(rowvalid[tid] + rowvalid[tid + 256]);
    #pragma unroll
    for (int o = 32; o > 0; o >>= 1) {
        s += __shfl_down(s, o);
        v += __shfl_down(v, o);
    }
    if (lane == 0) { sb[wid] = s; vb[wid] = v; }
    __syncthreads();
    if (tid == 0) {
        float ts = sb[0] + sb[1] + sb[2] + sb[3];
        float tv = vb[0] + vb[1] + vb[2] + vb[3];
        out[0] = ts / fmaxf(tv, 1.f);
    }
}

extern "C" void kernel_launch(void* const* d_in, const int* in_sizes, int n_in,
                              void* d_out, int out_size, void* d_ws, size_t ws_size,
                              hipStream_t stream) {
    const int*   ids   = (const int*)d_in[0];
    const float* feats = (const float*)d_in[1];
    float* out = (float*)d_out;

    char* ws = (char*)d_ws;
    float* cosm     = (float*)ws;                        // 1 MB
    float* rowloss  = (float*)(ws + (1u << 20));         // 2 KB
    int*   rowvalid = (int*)(ws + (1u << 20) + 2048);    // 2 KB

    hipLaunchKernelGGL(cos_fused, dim3(32 * 32), dim3(64), 0, stream, feats, cosm);
    hipLaunchKernelGGL(rows_kernel, dim3(B), dim3(256), 0, stream,
                       ids, cosm, rowloss, rowvalid);
    hipLaunchKernelGGL(finalize_kernel, dim3(1), dim3(256), 0, stream,
                       rowloss, rowvalid, out);
}